// Round 4
// baseline (1410.262 us; speedup 1.0000x reference)
//
#include <hip/hip_runtime.h>
#include <math.h>
#include <float.h>

#define B_   16
#define N_   4096
#define CIN  3
#define COUT 64
#define KNN  20
#define EPS_ 1e-5
#define SVC  64     // survivor capacity per (row, quarter) — per-lane scratch

// ---------------------------------------------------------------------------
// Workspace layout (5.5MB proven-safe footprint, identical to round 1):
//   [0,   216): double stats[27]    (Sum e[6], Sum e e^T upper-tri[21])
//   [256, 768): float scale[64], shift[64]
//   [1024, 1024 + B*N*KNN*4): int idx[B*N*KNN]                (5242880 B)
//   [5243904, +B*N*4): int perm[B*N]  (Morton row order)      (262144 B)
// ---------------------------------------------------------------------------

__device__ __forceinline__ unsigned expand10(unsigned v) {
    v = (v | (v << 16)) & 0x030000FFu;
    v = (v | (v << 8))  & 0x0300F00Fu;
    v = (v | (v << 4))  & 0x030C30C3u;
    v = (v | (v << 2))  & 0x09249249u;
    return v;
}
__device__ __forceinline__ unsigned quant10(float v) {
    int q = (int)((v + 4.0f) * 128.0f);
    return (unsigned)min(1023, max(0, q));
}

// ===========================================================================
// Kernel 0: per-batch Morton COUNTING sort (unchanged, verified)
// ===========================================================================
__global__ __launch_bounds__(1024) void morton_bucket_kernel(
    const float* __restrict__ x, int* __restrict__ perm)
{
    __shared__ int hist[1024];
    __shared__ int scanbuf[1024];
    __shared__ int offs[1024];
    const int b = blockIdx.x, tid = threadIdx.x;
    const float* xb = x + (size_t)b * N_ * CIN;

    hist[tid] = 0;
    __syncthreads();

    int keys[4];
#pragma unroll
    for (int i = 0; i < 4; ++i) {
        int p = tid + i * 1024;
        float v0 = xb[p * 3 + 0], v1 = xb[p * 3 + 1], v2 = xb[p * 3 + 2];
        unsigned m = (expand10(quant10(v0)) << 2) |
                     (expand10(quant10(v1)) << 1) |
                      expand10(quant10(v2));
        keys[i] = (int)(m >> 20);          // top 10 bits
        atomicAdd(&hist[keys[i]], 1);
    }
    __syncthreads();

    int v = hist[tid];
    scanbuf[tid] = v;
    __syncthreads();
    for (int off = 1; off < 1024; off <<= 1) {   // Hillis-Steele inclusive
        int t = (tid >= off) ? scanbuf[tid - off] : 0;
        __syncthreads();
        scanbuf[tid] += t;
        __syncthreads();
    }
    offs[tid] = scanbuf[tid] - v;                // exclusive base
    __syncthreads();

#pragma unroll
    for (int i = 0; i < 4; ++i) {
        int p = tid + i * 1024;
        int pos = atomicAdd(&offs[keys[i]], 1);
        perm[b * N_ + pos] = p;
    }
}

// ===========================================================================
// Kernel 1: exact-match KNN. Round-4: prefill-derived filter bound.
//
// Correctness chain (uses ONLY r1-verified machinery + 4-line extraction):
//  1. prefill (VERBATIM r1): bk = top-20 of 20 real quarter keys.
//  2. dpre = f32 d-part of bk[19]. key = sortable(d)*4096 + j is integer-
//     exact in f64, so s = trunc(key/4096) is exact; inverting the sortable
//     map gives the f32 d bit-exactly.
//  3. Any global top-20 winner w has <=19 keys below it anywhere, so
//     key_w <= max of ANY 20-key subset = bk[19]  =>  d_w <= dpre.
//     Gate "d <= dpre" therefore admits every winner. No epsilon.
//  4. scan (linear, prefill positions masked exactly as r1's shuffle-mask):
//     admitted candidates append their morton position (u16, if-converted,
//     no chain) to per-lane scratch; overflow past SVC runs the verified
//     insert inline (each candidate processed exactly once -> no dup keys).
//  5. drain: survivors go through the VERBATIM r1 f64 sorted-shift insert.
//     bk ends as top-20 of {prefill} u {admitted} which contains all
//     quarter winners -> the verified 2-round merge is unchanged-correct.
//  6. merge / idx write / BN stats: byte-identical to the verified code.
//
// Perf: per-candidate body is f32-only (~18 VALU); the 160cy f64 chain
// issues only in the per-lane-batched drain (~25-40/lane), breaking the
// wave-union saturation that held r1 at ~159cy/slot (r9/r10 finding).
// ===========================================================================
__global__ __launch_bounds__(512) void knn_f64_kernel(
    const float* __restrict__ x, const int* __restrict__ perm,
    int* __restrict__ idx_out, double* __restrict__ stats)
{
    __shared__ __align__(16) char smem[65536];
    float4* pts = (float4*)smem;                 // {x,y,z,bitcast(j)}
    double* scr = (double*)smem;                 // merge-scratch view

    const int b    = blockIdx.y;
    const int tid  = threadIdx.x;
    const int wave = tid >> 6;
    const int lane = tid & 63;
    const int r    = wave >> 2;     // row-group 0..1
    const int q    = wave & 3;      // interleave class: positions p&3==q
    const float* xb = x + (size_t)b * N_ * CIN;

    for (int p = tid; p < N_; p += 512) {
        int j = perm[b * N_ + p];                // coalesced
        pts[p] = make_float4(xb[j * 3 + 0], xb[j * 3 + 1], xb[j * 3 + 2],
                             __int_as_float(j));
    }
    __syncthreads();

    const int rowg = blockIdx.x * 128 + r * 64;  // wave's first row pos
    const float4 xf = pts[rowg + lane];
    const int jrow  = __float_as_int(xf.w);
    const float sqi = __fadd_rn(__fadd_rn(__fmul_rn(xf.x, xf.x),
                                          __fmul_rn(xf.y, xf.y)),
                                __fmul_rn(xf.z, xf.z));

    // exact f32 distance: bit-identical to the np/jax reference expansion
    auto mkd = [&](float4 p) -> float {
        float sqj = __fadd_rn(__fadd_rn(__fmul_rn(p.x, p.x),
                                        __fmul_rn(p.y, p.y)),
                              __fmul_rn(p.z, p.z));
        float dot = __fadd_rn(__fadd_rn(__fmul_rn(xf.x, p.x),
                                        __fmul_rn(xf.y, p.y)),
                              __fmul_rn(xf.z, p.z));
        return __fsub_rn(__fadd_rn(sqi, sqj), __fmul_rn(2.0f, dot));
    };
    auto mkkey = [&](float4 p) -> double {
        float d = mkd(p);
        unsigned u = __float_as_uint(d);
        unsigned s = u ^ (0x80000000u | (unsigned)((int)u >> 31));
        return fma((double)s, 4096.0,
                   (double)(unsigned)__float_as_int(p.w));
    };

    double bk[KNN];
#pragma unroll
    for (int k = 0; k < KNN; ++k) bk[k] = 1e300;     // sentinels (sorted)

    // VERBATIM r1 sorted-shift insert
    auto insert = [&](double key) {
        if (key < bk[KNN - 1]) {
            double m = key;                  // carries max(bk_old[i-1], key)
#pragma unroll
            for (int k = 0; k < KNN; ++k) {
                double old = bk[k];
                bk[k] = fmin(m, old);
                m     = fmax(old, m);
            }
        }
    };

    // ---- prefill (VERBATIM r1): 20 morton-adjacent quarter candidates ----
    const int ta = rowg >> 2;            // wave-uniform anchor (SGPR math)
#pragma unroll
    for (int k = 0; k < KNN; ++k)
        insert(mkkey(pts[4 * ((ta + k) & 1023) + q]));

    // ---- filter bound from prefill: dpre = d-part of bk[19], exact ----
    // bk[19] = s*4096 + j with s < 2^32, j < 2^12: integer-exact in f64.
    {
        // (scoped so nothing leaks)
    }
    double sp19 = trunc(bk[KNN - 1] * (1.0 / 4096.0));
    unsigned s19 = (unsigned)sp19;      // 20 real keys -> sp19 < 2^32, safe
    unsigned upre = (s19 >= 0x80000000u) ? (s19 ^ 0x80000000u) : ~s19;
    const float ub = __uint_as_float(upre);   // winners: d <= ub (proven)

    // ---- linear filtered scan of this quarter (1024 candidates) ----
    // prefill positions (t in [ta, ta+19] mod 1024) masked, as r1 masked
    // v<20 in its shuffled scan -> each candidate key enters bk at most once.
    unsigned short sv[SVC];
    unsigned cnt = 0;
    for (int t = 0; t < 1024; t += 4) {
#pragma unroll
        for (int i = 0; i < 4; ++i) {
            int ti = t + i;
            float4 a = pts[4 * ti + q];
            float d = mkd(a);
            bool notpre = ((unsigned)((ti - ta) & 1023) >= 20u);
            bool h = notpre && (d <= ub);
            bool app = h && (cnt < SVC);
            if (app) sv[cnt] = (unsigned short)(4 * ti + q);
            if (h && !app) insert(mkkey(a));   // rare overflow: exact path
            cnt += (unsigned)h;
        }
    }

    // ---- drain survivors through the verified insert (per-lane batched) --
    {
        unsigned stored = cnt < (unsigned)SVC ? cnt : (unsigned)SVC;
        for (unsigned i = 0; i < stored; ++i)
            insert(mkkey(pts[sv[i]]));
    }
    __syncthreads();    // scans done; pts dead (xf in regs) -> scr valid

    // ---- merge round A: q1 -> slot0, q3 -> slot1 (VERBATIM r1) ----
    if (q & 1) {
        int base = ((r * 2 + (q >> 1)) * 64 + lane) * KNN;
#pragma unroll
        for (int k = 0; k < KNN; ++k) scr[base + k] = bk[k];
    }
    __syncthreads();
    if (!(q & 1)) {                 // q0 absorbs q1; q2 absorbs q3
        int base = ((r * 2 + (q >> 1)) * 64 + lane) * KNN;
#pragma unroll
        for (int k = 0; k < KNN; ++k) insert(scr[base + k]);
    }
    __syncthreads();
    if (q == 2) {
        int base = ((r * 2 + 1) * 64 + lane) * KNN;
#pragma unroll
        for (int k = 0; k < KNN; ++k) scr[base + k] = bk[k];
    }
    __syncthreads();
    if (q == 0) {
        int base = ((r * 2 + 1) * 64 + lane) * KNN;
#pragma unroll
        for (int k = 0; k < KNN; ++k) insert(scr[base + k]);

        const long long row = (long long)b * N_ + jrow;
        int bi[KNN];
#pragma unroll
        for (int k = 0; k < KNN; ++k) {
            double sp = trunc(bk[k] * (1.0 / 4096.0));
            bi[k] = (int)(bk[k] - sp * 4096.0);
        }
#pragma unroll
        for (int k = 0; k < KNN; ++k) idx_out[row * KNN + k] = bi[k];

        float acc[27];
#pragma unroll
        for (int t = 0; t < 27; ++t) acc[t] = 0.0f;
#pragma unroll
        for (int k = 0; k < KNN; ++k) {
            const float* pj = xb + bi[k] * 3;
            float e[6] = { xf.x, xf.y, xf.z,
                           pj[0] - xf.x, pj[1] - xf.y, pj[2] - xf.z };
            int t = 6;
#pragma unroll
            for (int a = 0; a < 6; ++a) {
                acc[a] += e[a];
#pragma unroll
                for (int bb = a; bb < 6; ++bb) acc[t++] += e[a] * e[bb];
            }
        }
#pragma unroll
        for (int t = 0; t < 27; ++t) {
            float v = acc[t];
            v += __shfl_down(v, 32); v += __shfl_down(v, 16);
            v += __shfl_down(v, 8);  v += __shfl_down(v, 4);
            v += __shfl_down(v, 2);  v += __shfl_down(v, 1);
            acc[t] = v;
        }
        if (lane == 0) {
#pragma unroll
            for (int t = 0; t < 27; ++t) atomicAdd(&stats[t], (double)acc[t]);
        }
    }
}

// ===========================================================================
// Kernel 2: fold stats -> per-channel scale/shift (unchanged, verified)
// ===========================================================================
__global__ void bn_prep_kernel(
    const double* __restrict__ stats,
    const float* __restrict__ w1, const float* __restrict__ b1,
    const float* __restrict__ gamma, const float* __restrict__ beta,
    float* __restrict__ scale_shift)
{
    const int c = threadIdx.x;
    double s[6], S[6][6];
#pragma unroll
    for (int a = 0; a < 6; ++a) s[a] = stats[a];
    int t = 6;
#pragma unroll
    for (int a = 0; a < 6; ++a)
#pragma unroll
        for (int bb = a; bb < 6; ++bb) { S[a][bb] = stats[t]; S[bb][a] = stats[t]; ++t; }

    const double M = (double)B_ * N_ * KNN;
    double wc[6];
#pragma unroll
    for (int j = 0; j < 6; ++j) wc[j] = (double)w1[j * COUT + c];
    const double b1c = (double)b1[c];

    double sw = 0.0;
#pragma unroll
    for (int j = 0; j < 6; ++j) sw += s[j] * wc[j];
    double mean = sw / M + b1c;

    double qq = 0.0;
#pragma unroll
    for (int a = 0; a < 6; ++a)
#pragma unroll
        for (int bb = 0; bb < 6; ++bb) qq += S[a][bb] * wc[a] * wc[bb];
    double ex2 = (qq + 2.0 * b1c * sw) / M + b1c * b1c;
    double var = ex2 - mean * mean;

    double sc = (double)gamma[c] / sqrt(var + (double)EPS_);
    double sh = (double)beta[c] - mean * sc;
    scale_shift[c]        = (float)sc;
    scale_shift[COUT + c] = (float)sh;
}

// ===========================================================================
// Kernel 3: fused edge->lin1->BN->ReLU->lin2->max via split-bf16 MFMA
// (unchanged from round 1, verified: wave-private LDS, no barriers)
// ===========================================================================
typedef __attribute__((ext_vector_type(8))) short short8;
typedef __attribute__((ext_vector_type(4))) float f32x4;

__device__ __forceinline__ unsigned short f2bf_rn(float f) {
    unsigned u = __float_as_uint(f);
    unsigned lsb = (u >> 16) & 1u;
    return (unsigned short)((u + 0x7FFFu + lsb) >> 16);
}
__device__ __forceinline__ float bf2f(unsigned short h) {
    return __uint_as_float(((unsigned)h) << 16);
}

__global__ __launch_bounds__(256) void mlp_max_kernel(
    const float* __restrict__ x, const int* __restrict__ idx,
    const float* __restrict__ w1, const float* __restrict__ b1,
    const float* __restrict__ scale_shift,
    const float* __restrict__ w2, const float* __restrict__ b2,
    float* __restrict__ out)
{
    __shared__ __align__(16) unsigned short hbuf[4][2][16][136];

    const int tid  = threadIdx.x;
    const int wv   = tid >> 6;
    const int lane = tid & 63;
    const int g    = lane >> 4;      // 16-lane group (k-chunk select)
    const int r15  = lane & 15;      // row (A) / col (B,C) within tile

    const int R     = (blockIdx.x * 4 + wv) * 16;   // wave's first row
    const int bbase = (R >> 12) << 12;              // batch slab start row

    const int c  = lane;
    const float sc = scale_shift[c];
    const float sh = scale_shift[COUT + c];
    float w1p[6];
#pragma unroll
    for (int j = 0; j < 6; ++j) w1p[j] = w1[j * COUT + c] * sc;
    const float b1p = fmaf(b1[c], sc, sh);
    const float dw0 = w1p[0] - w1p[3];
    const float dw1 = w1p[1] - w1p[4];
    const float dw2 = w1p[2] - w1p[5];

    short8 Wh[2][4], Wl[2][4];
#pragma unroll
    for (int t = 0; t < 2; ++t)
#pragma unroll
        for (int n = 0; n < 4; ++n) {
            short8 hv, lv;
#pragma unroll
            for (int jj = 0; jj < 8; ++jj) {
                float w = w2[(t * 32 + g * 8 + jj) * COUT + n * 16 + r15];
                unsigned short hi = f2bf_rn(w);
                unsigned short lo = f2bf_rn(w - bf2f(hi));
                hv[jj] = (short)hi;
                lv[jj] = (short)lo;
            }
            Wh[t][n] = hv;
            Wl[t][n] = lv;
        }

    float base[16];
#pragma unroll
    for (int r = 0; r < 16; ++r) {
        const float* pi = x + (size_t)(R + r) * 3;
        float v = b1p;
        v = fmaf(pi[0], dw0, v);
        v = fmaf(pi[1], dw1, v);
        v = fmaf(pi[2], dw2, v);
        base[r] = v;
    }

    const int* idxp = idx + (size_t)R * KNN;

    f32x4 mx[4];
#pragma unroll
    for (int n = 0; n < 4; ++n) {
        mx[n][0] = -INFINITY; mx[n][1] = -INFINITY;
        mx[n][2] = -INFINITY; mx[n][3] = -INFINITY;
    }

    for (int k = 0; k < KNN; ++k) {
        unsigned short* hb = &hbuf[wv][k & 1][0][0];

#pragma unroll
        for (int r = 0; r < 16; ++r) {
            int j = idxp[r * KNN + k];                    // wave-uniform
            const float* pj = x + (size_t)(bbase + j) * 3;
            float h = base[r];
            h = fmaf(pj[0], w1p[3], h);
            h = fmaf(pj[1], w1p[4], h);
            h = fmaf(pj[2], w1p[5], h);
            h = fmaxf(h, 0.0f);
            unsigned short hi = f2bf_rn(h);
            unsigned short lo = f2bf_rn(h - bf2f(hi));
            hb[r * 136 + c]      = hi;
            hb[r * 136 + 64 + c] = lo;
        }

        const unsigned short* rpnt = hb + r15 * 136;
        short8 Ah0 = *(const short8*)(rpnt + g * 8);
        short8 Ah1 = *(const short8*)(rpnt + 32 + g * 8);
        short8 Al0 = *(const short8*)(rpnt + 64 + g * 8);
        short8 Al1 = *(const short8*)(rpnt + 96 + g * 8);

#pragma unroll
        for (int n = 0; n < 4; ++n) {
            f32x4 a = {0.0f, 0.0f, 0.0f, 0.0f};
            a = __builtin_amdgcn_mfma_f32_16x16x32_bf16(Ah0, Wh[0][n], a, 0, 0, 0);
            a = __builtin_amdgcn_mfma_f32_16x16x32_bf16(Ah1, Wh[1][n], a, 0, 0, 0);
            a = __builtin_amdgcn_mfma_f32_16x16x32_bf16(Al0, Wh[0][n], a, 0, 0, 0);
            a = __builtin_amdgcn_mfma_f32_16x16x32_bf16(Al1, Wh[1][n], a, 0, 0, 0);
            a = __builtin_amdgcn_mfma_f32_16x16x32_bf16(Ah0, Wl[0][n], a, 0, 0, 0);
            a = __builtin_amdgcn_mfma_f32_16x16x32_bf16(Ah1, Wl[1][n], a, 0, 0, 0);
            mx[n][0] = fmaxf(mx[n][0], a[0]);
            mx[n][1] = fmaxf(mx[n][1], a[1]);
            mx[n][2] = fmaxf(mx[n][2], a[2]);
            mx[n][3] = fmaxf(mx[n][3], a[3]);
        }
    }

    float b2v[4];
#pragma unroll
    for (int n = 0; n < 4; ++n) b2v[n] = b2[n * 16 + r15];
#pragma unroll
    for (int n = 0; n < 4; ++n)
#pragma unroll
        for (int rr = 0; rr < 4; ++rr)
            out[(size_t)(R + g * 4 + rr) * COUT + n * 16 + r15] =
                mx[n][rr] + b2v[n];
}

// ===========================================================================
extern "C" void kernel_launch(void* const* d_in, const int* in_sizes, int n_in,
                              void* d_out, int out_size, void* d_ws, size_t ws_size,
                              hipStream_t stream)
{
    const float* x     = (const float*)d_in[0];
    const float* w1    = (const float*)d_in[2];
    const float* b1    = (const float*)d_in[3];
    const float* gamma = (const float*)d_in[4];
    const float* beta  = (const float*)d_in[5];
    const float* w2    = (const float*)d_in[6];
    const float* b2    = (const float*)d_in[7];
    float* out = (float*)d_out;

    char*   ws          = (char*)d_ws;
    double* stats       = (double*)ws;
    float*  scale_shift = (float*)(ws + 256);
    int*    idx         = (int*)(ws + 1024);
    int*    perm        = (int*)(ws + 1024 + (size_t)B_ * N_ * KNN * 4);

    hipMemsetAsync(stats, 0, 27 * sizeof(double), stream);
    morton_bucket_kernel<<<B_, 1024, 0, stream>>>(x, perm);
    knn_f64_kernel<<<dim3(32, 16), 512, 0, stream>>>(x, perm, idx, stats);
    bn_prep_kernel<<<1, COUT, 0, stream>>>(stats, w1, b1, gamma, beta, scale_shift);
    mlp_max_kernel<<<(B_ * N_) / 64, 256, 0, stream>>>(x, idx, w1, b1, scale_shift,
                                                       w2, b2, out);
}

// Round 5
// 704.872 us; speedup vs baseline: 2.0007x; 2.0007x over previous
//
#include <hip/hip_runtime.h>
#include <math.h>
#include <float.h>

#define B_   16
#define N_   4096
#define CIN  3
#define COUT 64
#define KNN  20
#define EPS_ 1e-5
#define SVC  24     // survivor slots per lane (LDS [SVC][512] u16)

// ---------------------------------------------------------------------------
// Workspace layout (5.5MB proven-safe footprint, identical to round 1):
//   [0,   216): double stats[27]    (Sum e[6], Sum e e^T upper-tri[21])
//   [256, 768): float scale[64], shift[64]
//   [1024, 1024 + B*N*KNN*4): int idx[B*N*KNN]                (5242880 B)
//   [5243904, +B*N*4): int perm[B*N]  (Morton row order)      (262144 B)
//
// knn LDS (80KB dynamic, 2 blocks/CU):
//   [0,     16K): xs[4096] f32          [16K, 32K): ys   [32K, 48K): zs
//   [48K,   56K): j16[4096] u16 (orig row index)
//   [56K,   80K): sv[SVC][512] u16  (survivor morton positions; bank-free:
//                 addr = slot*1024 + tid*2 -> bank = tid/2, 2-way = free)
//   merge-scratch double view overlays [0, 40K) AFTER survivors drained.
// ---------------------------------------------------------------------------

__device__ __forceinline__ unsigned expand10(unsigned v) {
    v = (v | (v << 16)) & 0x030000FFu;
    v = (v | (v << 8))  & 0x0300F00Fu;
    v = (v | (v << 4))  & 0x030C30C3u;
    v = (v | (v << 2))  & 0x09249249u;
    return v;
}
__device__ __forceinline__ unsigned quant10(float v) {
    int q = (int)((v + 4.0f) * 128.0f);
    return (unsigned)min(1023, max(0, q));
}

// ===========================================================================
// Kernel 0: per-batch Morton COUNTING sort (unchanged, verified)
// ===========================================================================
__global__ __launch_bounds__(1024) void morton_bucket_kernel(
    const float* __restrict__ x, int* __restrict__ perm)
{
    __shared__ int hist[1024];
    __shared__ int scanbuf[1024];
    __shared__ int offs[1024];
    const int b = blockIdx.x, tid = threadIdx.x;
    const float* xb = x + (size_t)b * N_ * CIN;

    hist[tid] = 0;
    __syncthreads();

    int keys[4];
#pragma unroll
    for (int i = 0; i < 4; ++i) {
        int p = tid + i * 1024;
        float v0 = xb[p * 3 + 0], v1 = xb[p * 3 + 1], v2 = xb[p * 3 + 2];
        unsigned m = (expand10(quant10(v0)) << 2) |
                     (expand10(quant10(v1)) << 1) |
                      expand10(quant10(v2));
        keys[i] = (int)(m >> 20);          // top 10 bits
        atomicAdd(&hist[keys[i]], 1);
    }
    __syncthreads();

    int v = hist[tid];
    scanbuf[tid] = v;
    __syncthreads();
    for (int off = 1; off < 1024; off <<= 1) {   // Hillis-Steele inclusive
        int t = (tid >= off) ? scanbuf[tid - off] : 0;
        __syncthreads();
        scanbuf[tid] += t;
        __syncthreads();
    }
    offs[tid] = scanbuf[tid] - v;                // exclusive base
    __syncthreads();

#pragma unroll
    for (int i = 0; i < 4; ++i) {
        int p = tid + i * 1024;
        int pos = atomicAdd(&offs[keys[i]], 1);
        perm[b * N_ + pos] = p;
    }
}

// ===========================================================================
// Kernel 1: exact-match KNN. Round-5 = round-4 VERIFIED logic (prefill-
// derived filter bound, absmax 0.03125) with the survivor list moved from
// per-lane scratch (localMem — r4's 3.4x regression: occupancy 18%, 4.6M
// bank conflicts, VMEM round-trips) into conflict-free LDS, and the point
// tile SoA-ized to make room (80KB total, still 2 blocks/CU).
//
// Correctness chain unchanged from r4 (harness-verified):
//  1. prefill: bk = top-20 of 20 real quarter keys (verbatim).
//  2. ub = exact f32 d-part of bk[19] (integer-exact f64 decode).
//  3. winner w: key_w <= any-20-subset max = bk[19] => d_w <= ub. No eps.
//  4. scan: prefill-masked, d <= ub appends morton pos; overflow past SVC
//     runs the verified insert inline (each candidate exactly once).
//  5. drain through verified insert; 2-round merge / extraction / BN stats
//     byte-identical.
// ===========================================================================
__global__ __launch_bounds__(512) void knn_f64_kernel(
    const float* __restrict__ x, const int* __restrict__ perm,
    int* __restrict__ idx_out, double* __restrict__ stats)
{
    extern __shared__ __align__(16) char smem[];
    float* xs = (float*)smem;                              // [4096]
    float* ys = (float*)(smem + 16384);                    // [4096]
    float* zs = (float*)(smem + 32768);                    // [4096]
    unsigned short* j16 = (unsigned short*)(smem + 49152); // [4096]
    unsigned short* svb = (unsigned short*)(smem + 57344); // [SVC][512]
    double* scr = (double*)smem;                           // merge view

    const int b    = blockIdx.y;
    const int tid  = threadIdx.x;
    const int wave = tid >> 6;
    const int lane = tid & 63;
    const int r    = wave >> 2;     // row-group 0..1
    const int q    = wave & 3;      // interleave class: positions p&3==q
    const float* xb = x + (size_t)b * N_ * CIN;

    for (int p = tid; p < N_; p += 512) {
        int j = perm[b * N_ + p];                // coalesced
        xs[p] = xb[j * 3 + 0];
        ys[p] = xb[j * 3 + 1];
        zs[p] = xb[j * 3 + 2];
        j16[p] = (unsigned short)j;
    }
    __syncthreads();

    const int rowg = blockIdx.x * 128 + r * 64;  // wave's first row pos
    const int rp   = rowg + lane;
    const float xfx = xs[rp], xfy = ys[rp], xfz = zs[rp];
    const int jrow  = j16[rp];
    const float sqi = __fadd_rn(__fadd_rn(__fmul_rn(xfx, xfx),
                                          __fmul_rn(xfy, xfy)),
                                __fmul_rn(xfz, xfz));

    // exact f32 distance: bit-identical to the np/jax reference expansion
    auto mkd3 = [&](float px, float py, float pz) -> float {
        float sqj = __fadd_rn(__fadd_rn(__fmul_rn(px, px),
                                        __fmul_rn(py, py)),
                              __fmul_rn(pz, pz));
        float dot = __fadd_rn(__fadd_rn(__fmul_rn(xfx, px),
                                        __fmul_rn(xfy, py)),
                              __fmul_rn(xfz, pz));
        return __fsub_rn(__fadd_rn(sqi, sqj), __fmul_rn(2.0f, dot));
    };
    auto mkkey3 = [&](float px, float py, float pz, int j) -> double {
        float d = mkd3(px, py, pz);
        unsigned u = __float_as_uint(d);
        unsigned s = u ^ (0x80000000u | (unsigned)((int)u >> 31));
        return fma((double)s, 4096.0, (double)(unsigned)j);
    };

    double bk[KNN];
#pragma unroll
    for (int k = 0; k < KNN; ++k) bk[k] = 1e300;     // sentinels (sorted)

    // VERBATIM verified sorted-shift insert
    auto insert = [&](double key) {
        if (key < bk[KNN - 1]) {
            double m = key;                  // carries max(bk_old[i-1], key)
#pragma unroll
            for (int k = 0; k < KNN; ++k) {
                double old = bk[k];
                bk[k] = fmin(m, old);
                m     = fmax(old, m);
            }
        }
    };

    // ---- prefill (verified): 20 morton-adjacent quarter candidates ----
    const int ta = rowg >> 2;            // wave-uniform anchor
#pragma unroll
    for (int k = 0; k < KNN; ++k) {
        int p = 4 * ((ta + k) & 1023) + q;
        insert(mkkey3(xs[p], ys[p], zs[p], j16[p]));
    }

    // ---- filter bound from prefill (verified): exact d-part of bk[19] ----
    double sp19 = trunc(bk[KNN - 1] * (1.0 / 4096.0));
    unsigned s19 = (unsigned)sp19;
    unsigned upre = (s19 >= 0x80000000u) ? (s19 ^ 0x80000000u) : ~s19;
    const float ub = __uint_as_float(upre);   // winners: d <= ub (proven)

    // ---- linear filtered scan of this quarter (verified logic) ----
    unsigned cnt = 0;
    for (int t = 0; t < 1024; t += 4) {
#pragma unroll
        for (int i = 0; i < 4; ++i) {
            int ti = t + i;
            int p  = 4 * ti + q;
            float px = xs[p], py = ys[p], pz = zs[p];
            float d = mkd3(px, py, pz);
            bool notpre = ((unsigned)((ti - ta) & 1023) >= 20u);
            bool h = notpre && (d <= ub);
            bool app = h && (cnt < SVC);
            if (app) svb[cnt * 512 + tid] = (unsigned short)p;
            if (h && !app) insert(mkkey3(px, py, pz, j16[p]));  // rare
            cnt += (unsigned)h;
        }
    }

    // ---- drain survivors through the verified insert ----
    {
        unsigned stored = cnt < (unsigned)SVC ? cnt : (unsigned)SVC;
        for (unsigned i = 0; i < stored; ++i) {
            int p = svb[i * 512 + tid];
            insert(mkkey3(xs[p], ys[p], zs[p], j16[p]));
        }
    }
    __syncthreads();    // scans done; SoA tile dead -> scr valid

    // ---- merge round A: q1 -> slot0, q3 -> slot1 (verbatim verified) ----
    if (q & 1) {
        int base = ((r * 2 + (q >> 1)) * 64 + lane) * KNN;
#pragma unroll
        for (int k = 0; k < KNN; ++k) scr[base + k] = bk[k];
    }
    __syncthreads();
    if (!(q & 1)) {                 // q0 absorbs q1; q2 absorbs q3
        int base = ((r * 2 + (q >> 1)) * 64 + lane) * KNN;
#pragma unroll
        for (int k = 0; k < KNN; ++k) insert(scr[base + k]);
    }
    __syncthreads();
    if (q == 2) {
        int base = ((r * 2 + 1) * 64 + lane) * KNN;
#pragma unroll
        for (int k = 0; k < KNN; ++k) scr[base + k] = bk[k];
    }
    __syncthreads();
    if (q == 0) {
        int base = ((r * 2 + 1) * 64 + lane) * KNN;
#pragma unroll
        for (int k = 0; k < KNN; ++k) insert(scr[base + k]);

        const long long row = (long long)b * N_ + jrow;
        int bi[KNN];
#pragma unroll
        for (int k = 0; k < KNN; ++k) {
            double sp = trunc(bk[k] * (1.0 / 4096.0));
            bi[k] = (int)(bk[k] - sp * 4096.0);
        }
#pragma unroll
        for (int k = 0; k < KNN; ++k) idx_out[row * KNN + k] = bi[k];

        float acc[27];
#pragma unroll
        for (int t = 0; t < 27; ++t) acc[t] = 0.0f;
#pragma unroll
        for (int k = 0; k < KNN; ++k) {
            const float* pj = xb + bi[k] * 3;
            float e[6] = { xfx, xfy, xfz,
                           pj[0] - xfx, pj[1] - xfy, pj[2] - xfz };
            int t = 6;
#pragma unroll
            for (int a = 0; a < 6; ++a) {
                acc[a] += e[a];
#pragma unroll
                for (int bb = a; bb < 6; ++bb) acc[t++] += e[a] * e[bb];
            }
        }
#pragma unroll
        for (int t = 0; t < 27; ++t) {
            float v = acc[t];
            v += __shfl_down(v, 32); v += __shfl_down(v, 16);
            v += __shfl_down(v, 8);  v += __shfl_down(v, 4);
            v += __shfl_down(v, 2);  v += __shfl_down(v, 1);
            acc[t] = v;
        }
        if (lane == 0) {
#pragma unroll
            for (int t = 0; t < 27; ++t) atomicAdd(&stats[t], (double)acc[t]);
        }
    }
}

// ===========================================================================
// Kernel 2: fold stats -> per-channel scale/shift (unchanged, verified)
// ===========================================================================
__global__ void bn_prep_kernel(
    const double* __restrict__ stats,
    const float* __restrict__ w1, const float* __restrict__ b1,
    const float* __restrict__ gamma, const float* __restrict__ beta,
    float* __restrict__ scale_shift)
{
    const int c = threadIdx.x;
    double s[6], S[6][6];
#pragma unroll
    for (int a = 0; a < 6; ++a) s[a] = stats[a];
    int t = 6;
#pragma unroll
    for (int a = 0; a < 6; ++a)
#pragma unroll
        for (int bb = a; bb < 6; ++bb) { S[a][bb] = stats[t]; S[bb][a] = stats[t]; ++t; }

    const double M = (double)B_ * N_ * KNN;
    double wc[6];
#pragma unroll
    for (int j = 0; j < 6; ++j) wc[j] = (double)w1[j * COUT + c];
    const double b1c = (double)b1[c];

    double sw = 0.0;
#pragma unroll
    for (int j = 0; j < 6; ++j) sw += s[j] * wc[j];
    double mean = sw / M + b1c;

    double qq = 0.0;
#pragma unroll
    for (int a = 0; a < 6; ++a)
#pragma unroll
        for (int bb = 0; bb < 6; ++bb) qq += S[a][bb] * wc[a] * wc[bb];
    double ex2 = (qq + 2.0 * b1c * sw) / M + b1c * b1c;
    double var = ex2 - mean * mean;

    double sc = (double)gamma[c] / sqrt(var + (double)EPS_);
    double sh = (double)beta[c] - mean * sc;
    scale_shift[c]        = (float)sc;
    scale_shift[COUT + c] = (float)sh;
}

// ===========================================================================
// Kernel 3: fused edge->lin1->BN->ReLU->lin2->max via split-bf16 MFMA
// (unchanged, verified: wave-private LDS, no barriers, 24 MFMA/k-tile)
// ===========================================================================
typedef __attribute__((ext_vector_type(8))) short short8;
typedef __attribute__((ext_vector_type(4))) float f32x4;

__device__ __forceinline__ unsigned short f2bf_rn(float f) {
    unsigned u = __float_as_uint(f);
    unsigned lsb = (u >> 16) & 1u;
    return (unsigned short)((u + 0x7FFFu + lsb) >> 16);
}
__device__ __forceinline__ float bf2f(unsigned short h) {
    return __uint_as_float(((unsigned)h) << 16);
}

__global__ __launch_bounds__(256) void mlp_max_kernel(
    const float* __restrict__ x, const int* __restrict__ idx,
    const float* __restrict__ w1, const float* __restrict__ b1,
    const float* __restrict__ scale_shift,
    const float* __restrict__ w2, const float* __restrict__ b2,
    float* __restrict__ out)
{
    __shared__ __align__(16) unsigned short hbuf[4][2][16][136];

    const int tid  = threadIdx.x;
    const int wv   = tid >> 6;
    const int lane = tid & 63;
    const int g    = lane >> 4;      // 16-lane group (k-chunk select)
    const int r15  = lane & 15;      // row (A) / col (B,C) within tile

    const int R     = (blockIdx.x * 4 + wv) * 16;   // wave's first row
    const int bbase = (R >> 12) << 12;              // batch slab start row

    const int c  = lane;
    const float sc = scale_shift[c];
    const float sh = scale_shift[COUT + c];
    float w1p[6];
#pragma unroll
    for (int j = 0; j < 6; ++j) w1p[j] = w1[j * COUT + c] * sc;
    const float b1p = fmaf(b1[c], sc, sh);
    const float dw0 = w1p[0] - w1p[3];
    const float dw1 = w1p[1] - w1p[4];
    const float dw2 = w1p[2] - w1p[5];

    short8 Wh[2][4], Wl[2][4];
#pragma unroll
    for (int t = 0; t < 2; ++t)
#pragma unroll
        for (int n = 0; n < 4; ++n) {
            short8 hv, lv;
#pragma unroll
            for (int jj = 0; jj < 8; ++jj) {
                float w = w2[(t * 32 + g * 8 + jj) * COUT + n * 16 + r15];
                unsigned short hi = f2bf_rn(w);
                unsigned short lo = f2bf_rn(w - bf2f(hi));
                hv[jj] = (short)hi;
                lv[jj] = (short)lo;
            }
            Wh[t][n] = hv;
            Wl[t][n] = lv;
        }

    float base[16];
#pragma unroll
    for (int r = 0; r < 16; ++r) {
        const float* pi = x + (size_t)(R + r) * 3;
        float v = b1p;
        v = fmaf(pi[0], dw0, v);
        v = fmaf(pi[1], dw1, v);
        v = fmaf(pi[2], dw2, v);
        base[r] = v;
    }

    const int* idxp = idx + (size_t)R * KNN;

    f32x4 mx[4];
#pragma unroll
    for (int n = 0; n < 4; ++n) {
        mx[n][0] = -INFINITY; mx[n][1] = -INFINITY;
        mx[n][2] = -INFINITY; mx[n][3] = -INFINITY;
    }

    for (int k = 0; k < KNN; ++k) {
        unsigned short* hb = &hbuf[wv][k & 1][0][0];

#pragma unroll
        for (int r = 0; r < 16; ++r) {
            int j = idxp[r * KNN + k];                    // wave-uniform
            const float* pj = x + (size_t)(bbase + j) * 3;
            float h = base[r];
            h = fmaf(pj[0], w1p[3], h);
            h = fmaf(pj[1], w1p[4], h);
            h = fmaf(pj[2], w1p[5], h);
            h = fmaxf(h, 0.0f);
            unsigned short hi = f2bf_rn(h);
            unsigned short lo = f2bf_rn(h - bf2f(hi));
            hb[r * 136 + c]      = hi;
            hb[r * 136 + 64 + c] = lo;
        }

        const unsigned short* rpnt = hb + r15 * 136;
        short8 Ah0 = *(const short8*)(rpnt + g * 8);
        short8 Ah1 = *(const short8*)(rpnt + 32 + g * 8);
        short8 Al0 = *(const short8*)(rpnt + 64 + g * 8);
        short8 Al1 = *(const short8*)(rpnt + 96 + g * 8);

#pragma unroll
        for (int n = 0; n < 4; ++n) {
            f32x4 a = {0.0f, 0.0f, 0.0f, 0.0f};
            a = __builtin_amdgcn_mfma_f32_16x16x32_bf16(Ah0, Wh[0][n], a, 0, 0, 0);
            a = __builtin_amdgcn_mfma_f32_16x16x32_bf16(Ah1, Wh[1][n], a, 0, 0, 0);
            a = __builtin_amdgcn_mfma_f32_16x16x32_bf16(Al0, Wh[0][n], a, 0, 0, 0);
            a = __builtin_amdgcn_mfma_f32_16x16x32_bf16(Al1, Wh[1][n], a, 0, 0, 0);
            a = __builtin_amdgcn_mfma_f32_16x16x32_bf16(Ah0, Wl[0][n], a, 0, 0, 0);
            a = __builtin_amdgcn_mfma_f32_16x16x32_bf16(Ah1, Wl[1][n], a, 0, 0, 0);
            mx[n][0] = fmaxf(mx[n][0], a[0]);
            mx[n][1] = fmaxf(mx[n][1], a[1]);
            mx[n][2] = fmaxf(mx[n][2], a[2]);
            mx[n][3] = fmaxf(mx[n][3], a[3]);
        }
    }

    float b2v[4];
#pragma unroll
    for (int n = 0; n < 4; ++n) b2v[n] = b2[n * 16 + r15];
#pragma unroll
    for (int n = 0; n < 4; ++n)
#pragma unroll
        for (int rr = 0; rr < 4; ++rr)
            out[(size_t)(R + g * 4 + rr) * COUT + n * 16 + r15] =
                mx[n][rr] + b2v[n];
}

// ===========================================================================
extern "C" void kernel_launch(void* const* d_in, const int* in_sizes, int n_in,
                              void* d_out, int out_size, void* d_ws, size_t ws_size,
                              hipStream_t stream)
{
    const float* x     = (const float*)d_in[0];
    const float* w1    = (const float*)d_in[2];
    const float* b1    = (const float*)d_in[3];
    const float* gamma = (const float*)d_in[4];
    const float* beta  = (const float*)d_in[5];
    const float* w2    = (const float*)d_in[6];
    const float* b2    = (const float*)d_in[7];
    float* out = (float*)d_out;

    char*   ws          = (char*)d_ws;
    double* stats       = (double*)ws;
    float*  scale_shift = (float*)(ws + 256);
    int*    idx         = (int*)(ws + 1024);
    int*    perm        = (int*)(ws + 1024 + (size_t)B_ * N_ * KNN * 4);

    // one-time opt-in for >64KB dynamic LDS (gfx950 allows up to 160KB/WG);
    // host-side, not a stream op -> graph-capture-safe. Errors ignored.
    static int _lds_once = []() {
        (void)hipFuncSetAttribute((const void*)knn_f64_kernel,
                                  hipFuncAttributeMaxDynamicSharedMemorySize,
                                  131072);
        return 0;
    }();
    (void)_lds_once;

    hipMemsetAsync(stats, 0, 27 * sizeof(double), stream);
    morton_bucket_kernel<<<B_, 1024, 0, stream>>>(x, perm);
    knn_f64_kernel<<<dim3(32, 16), 512, 81920, stream>>>(x, perm, idx, stats);
    bn_prep_kernel<<<1, COUT, 0, stream>>>(stats, w1, b1, gamma, beta, scale_shift);
    mlp_max_kernel<<<(B_ * N_) / 64, 256, 0, stream>>>(x, idx, w1, b1, scale_shift,
                                                       w2, b2, out);
}